// Round 8
// baseline (473.680 us; speedup 1.0000x reference)
//
#include <hip/hip_runtime.h>
#include <hip/hip_bf16.h>
#include <stdint.h>

// ---------------------------------------------------------------------------
// StaticGNN: SAGEConv(mean) -> ReLU -> Linear -> ReLU -> SAGEConv(mean) ->
//            ReLU -> global_mean_pool -> fc
// Round 8: fp8(e4m3) shadow copies of node features feed the neighbor
// gather (halves the 2.4 TB/s-pinned random-gather traffic); self-term,
// weights, accumulation stay bf16/fp32. fc fused into conv1p via last-block
// ticket. 4 dispatches: memset, prep, conv01, conv1p.
// ---------------------------------------------------------------------------

typedef __attribute__((ext_vector_type(8))) short short8;
typedef __attribute__((ext_vector_type(4))) float f32x4;
typedef __attribute__((ext_vector_type(2))) float f32x2;

__device__ __forceinline__ float bits2f(uint32_t b) {
    union { uint32_t u; float f; } c; c.u = b; return c.f;
}
__device__ __forceinline__ unsigned short f2bf(float f) {
    __hip_bfloat16 h = __float2bfloat16(f);
    union { __hip_bfloat16 h; unsigned short u; } c; c.h = h; return c.u;
}
__device__ __forceinline__ uint32_t pack2bf(float a, float b) {
    return (uint32_t)f2bf(a) | ((uint32_t)f2bf(b) << 16);
}
// 4 floats -> 4 fp8 e4m3 packed in a uint (HW cvt, OCP on gfx950)
__device__ __forceinline__ uint32_t pk4fp8(float f0, float f1, float f2, float f3) {
    int o = 0;
    o = __builtin_amdgcn_cvt_pk_fp8_f32(f0, f1, o, false);
    o = __builtin_amdgcn_cvt_pk_fp8_f32(f2, f3, o, true);
    return (uint32_t)o;
}
// accumulate 8 fp8 values (uint2) into fp32 acc
__device__ __forceinline__ void acc8f8(float* a, uint2 v) {
    f32x2 p0 = __builtin_amdgcn_cvt_pk_f32_fp8((int)v.x, false);
    f32x2 p1 = __builtin_amdgcn_cvt_pk_f32_fp8((int)v.x, true);
    f32x2 p2 = __builtin_amdgcn_cvt_pk_f32_fp8((int)v.y, false);
    f32x2 p3 = __builtin_amdgcn_cvt_pk_f32_fp8((int)v.y, true);
    a[0] += p0.x; a[1] += p0.y; a[2] += p1.x; a[3] += p1.y;
    a[4] += p2.x; a[5] += p2.y; a[6] += p3.x; a[7] += p3.y;
}

// wave-local dtype detection
__device__ __forceinline__ void detect_flags(const unsigned short* x,
                                             const int* ei,
                                             int& isbf, int& is64) {
    int lane = threadIdx.x & 63;
    unsigned short h = x[lane];
    int e = (h >> 7) & 0xFF;
    unsigned long long mbf = __ballot(e >= 102 && e <= 137);
    unsigned long long m64 = __ballot(ei[2 * lane + 1] != 0);
    isbf = (__popcll(mbf) >= 52) ? 1 : 0;
    is64 = (m64 == 0ULL) ? 1 : 0;
}

// ----- fused prep: flags + bucket-adjacency + wcvt + x->fp8 (+bf16) ------
#define WB_W0L 0
#define WB_W0R 16384
#define WB_W1  32768
#define WB_W1L 49152
#define WB_W1R 65536
#define WB_TOTAL 81920
#define CF_B0L 0
#define CF_B1  128
#define CF_B1L 256
#define CF_FCW 384
#define CF_FCB 768
#define CF_TOTAL 771

__global__ __launch_bounds__(256) void prep_kernel(
    const void* x, const int* __restrict__ ei,
    const void* s0, const void* s1, const void* s2, const void* s3,
    const void* s4, const void* f0, const void* f1, const void* f2,
    const void* f3, const void* f4,
    unsigned short* __restrict__ Hb, uint2* __restrict__ Xf8,
    unsigned short* __restrict__ wb,
    float* __restrict__ cf, int* __restrict__ cnt, int* __restrict__ nbr,
    int* __restrict__ flags, int n8, int E, int EG, int WC) {
    int isbf, is64;
    detect_flags((const unsigned short*)x, ei, isbf, is64);
    int b = blockIdx.x;
    if (b == 0 && threadIdx.x == 0) { flags[0] = isbf; flags[1] = is64; }

    if (b < EG) {
        // bucket-adjacency build: one pass over edges
        int e = b * 256 + threadIdx.x;
        if (e >= E) return;
        int s, d;
        if (is64) { s = ei[2 * e]; d = ei[2 * (E + e)]; }
        else      { s = ei[e];     d = ei[E + e]; }
        int pos = atomicAdd(&cnt[d], 1);
        if (pos < 64) nbr[((size_t)d << 6) + pos] = s;
    } else if (b < EG + WC) {
        int i = (b - EG) * 256 + threadIdx.x;
        if (i < WB_TOTAL) {
            const void* p; int k = i & 16383;
            switch (i >> 14) {
                case 0: p = s0; break;
                case 1: p = s1; break;
                case 2: p = s2; break;
                case 3: p = s3; break;
                default: p = s4; break;
            }
            wb[i] = isbf ? ((const unsigned short*)p)[k]
                         : f2bf(((const float*)p)[k]);
        } else {
            int j = i - WB_TOTAL;
            if (j >= CF_TOTAL) return;
            const void* p; int k;
            if      (j < CF_B1)  { p = f0; k = j; }
            else if (j < CF_B1L) { p = f1; k = j - CF_B1; }
            else if (j < CF_FCW) { p = f2; k = j - CF_B1L; }
            else if (j < CF_FCB) { p = f3; k = j - CF_FCW; }
            else                 { p = f4; k = j - CF_FCB; }
            cf[j] = isbf ? bits2f((uint32_t)((const unsigned short*)p)[k] << 16)
                         : ((const float*)p)[k];
        }
    } else {
        // x -> fp8 shadow (always); fp32 input additionally -> bf16 Hb
        int i = (b - EG - WC) * 256 + threadIdx.x;
        if (i >= n8) return;
        float f[8];
        if (isbf) {
            uint4 d = ((const uint4*)x)[i];
            f[0] = bits2f(d.x << 16); f[1] = bits2f(d.x & 0xffff0000u);
            f[2] = bits2f(d.y << 16); f[3] = bits2f(d.y & 0xffff0000u);
            f[4] = bits2f(d.z << 16); f[5] = bits2f(d.z & 0xffff0000u);
            f[6] = bits2f(d.w << 16); f[7] = bits2f(d.w & 0xffff0000u);
        } else {
            float4 a = ((const float4*)x)[2 * i];
            float4 c = ((const float4*)x)[2 * i + 1];
            f[0] = a.x; f[1] = a.y; f[2] = a.z; f[3] = a.w;
            f[4] = c.x; f[5] = c.y; f[6] = c.z; f[7] = c.w;
            uint4 d;
            d.x = pack2bf(f[0], f[1]); d.y = pack2bf(f[2], f[3]);
            d.z = pack2bf(f[4], f[5]); d.w = pack2bf(f[6], f[7]);
            ((uint4*)Hb)[i] = d;
        }
        uint2 o8;
        o8.x = pk4fp8(f[0], f[1], f[2], f[3]);
        o8.y = pk4fp8(f[4], f[5], f[6], f[7]);
        Xf8[i] = o8;
    }
}

// ----- fused conv core: 16 rows/block, 4 waves ---------------------------
// gather reads the fp8 shadow (128 B/row); self-term reads bf16.
template <bool LIN1, bool POOL>
__device__ __forceinline__ void conv_core(
    const void* xsel, const unsigned short* __restrict__ Hbuf,
    const uint2* __restrict__ G8,
    const int* __restrict__ cnt, const int* __restrict__ nbr,
    const unsigned short* __restrict__ Wl, const unsigned short* __restrict__ Wr,
    const float* __restrict__ bias,
    const unsigned short* __restrict__ W2, const float* __restrict__ bias2,
    unsigned short* __restrict__ Hdst, uint2* __restrict__ Hdst8,
    float* __restrict__ pool, const int* __restrict__ batch,
    const int* __restrict__ flags, int N,
    int* __restrict__ done, const float* __restrict__ fcW,
    const float* __restrict__ fcb, void* __restrict__ out, int G) {
    __shared__ unsigned short bufA[16 * 136];
    __shared__ unsigned short bufB[LIN1 ? 16 * 136 : 1];
    __shared__ float pbuf[POOL ? 512 : 1];
    __shared__ int gst_s[34];
    __shared__ int ticket_s;
    const int t = threadIdx.x;
    const int lane = t & 63;
    const int w = t >> 6;
    const int l15 = lane & 15;
    const int kq = lane >> 4;
    const int m0 = blockIdx.x * 16;

    const int flags0 = flags[0];
    const unsigned short* Hs = flags0 ? (const unsigned short*)xsel : Hbuf;

    int f64 = 0, gmin = 0, g[4];
    if (POOL) {
        f64 = flags[1];
        gmin = f64 ? batch[2 * m0] : batch[m0];
#pragma unroll
        for (int r = 0; r < 4; r++) {
            int gr = m0 + kq * 4 + r;
            g[r] = (gr < N) ? (f64 ? batch[2 * gr] : batch[gr]) : -1;
        }
        for (int i = t; i < 512; i += 256) pbuf[i] = 0.f;
    }

    // prefetch x-frag (overlaps gather latency); clamp tail rows
    short8 xf[4];
    {
        int xr = m0 + l15; if (xr >= N) xr = N - 1;
        const unsigned short* xrow = Hs + (size_t)xr * 128 + kq * 8;
#pragma unroll
        for (int kc = 0; kc < 4; kc++) xf[kc] = *(const short8*)(xrow + kc * 32);
    }
    float bc[2];
    const int nt0 = w * 2;
    bc[0] = bias[nt0 * 16 + l15];
    bc[1] = bias[(nt0 + 1) * 16 + l15];

    // ---- phase 1: fp8 gather-mean; quarter kq of wave w handles row w*4+kq
    {
        const int row = w * 4 + kq;
        const int node = m0 + row;
        float a[8] = {0.f, 0.f, 0.f, 0.f, 0.f, 0.f, 0.f, 0.f};
        float invd = 0.f;
        if (node < N) {
            int dcnt = cnt[node];
            invd = 1.f / fmaxf((float)dcnt, 1.f);
            if (dcnt > 64) dcnt = 64;
            const int* nrow = nbr + ((size_t)node << 6);
            for (int base = 0; base < dcnt; base += 16) {
                int c = dcnt - base; if (c > 16) c = 16;
                int idx = (l15 < c) ? nrow[base + l15] : 0;
                int it = 0;
                for (; it + 4 <= c; it += 4) {
                    int j0 = __shfl(idx, kq * 16 + it, 64);
                    int j1 = __shfl(idx, kq * 16 + it + 1, 64);
                    int j2 = __shfl(idx, kq * 16 + it + 2, 64);
                    int j3 = __shfl(idx, kq * 16 + it + 3, 64);
                    uint2 v0 = G8[(size_t)j0 * 16 + l15];
                    uint2 v1 = G8[(size_t)j1 * 16 + l15];
                    uint2 v2 = G8[(size_t)j2 * 16 + l15];
                    uint2 v3 = G8[(size_t)j3 * 16 + l15];
                    acc8f8(a, v0); acc8f8(a, v1); acc8f8(a, v2); acc8f8(a, v3);
                }
                for (; it < c; ++it) {
                    int j = __shfl(idx, kq * 16 + it, 64);
                    acc8f8(a, G8[(size_t)j * 16 + l15]);
                }
            }
        }
        uint4 o;
        o.x = pack2bf(a[0] * invd, a[1] * invd);
        o.y = pack2bf(a[2] * invd, a[3] * invd);
        o.z = pack2bf(a[4] * invd, a[5] * invd);
        o.w = pack2bf(a[6] * invd, a[7] * invd);
        *(uint4*)(bufA + row * 136 + l15 * 8) = o;
    }
    __syncthreads();

    // ---- phase 2: MFMA; wave w owns col tiles nt0, nt0+1
    short8 af[4];
#pragma unroll
    for (int kc = 0; kc < 4; kc++)
        af[kc] = *(const short8*)(bufA + l15 * 136 + kc * 32 + kq * 8);

    f32x4 acc[2];
    acc[0] = (f32x4){0.f, 0.f, 0.f, 0.f};
    acc[1] = (f32x4){0.f, 0.f, 0.f, 0.f};
#pragma unroll
    for (int kc = 0; kc < 4; kc++) {
#pragma unroll
        for (int u = 0; u < 2; u++) {
            const size_t woff = (size_t)((nt0 + u) * 16 + l15) * 128 + kc * 32 + kq * 8;
            acc[u] = __builtin_amdgcn_mfma_f32_16x16x32_bf16(
                xf[kc], *(const short8*)(Wr + woff), acc[u], 0, 0, 0);
            acc[u] = __builtin_amdgcn_mfma_f32_16x16x32_bf16(
                af[kc], *(const short8*)(Wl + woff), acc[u], 0, 0, 0);
        }
    }

    if (LIN1) {
#pragma unroll
        for (int u = 0; u < 2; u++) {
#pragma unroll
            for (int r = 0; r < 4; r++) {
                bufB[(kq * 4 + r) * 136 + (nt0 + u) * 16 + l15] =
                    f2bf(fmaxf(acc[u][r] + bc[u], 0.f));
            }
        }
        __syncthreads();
        short8 hf[4];
#pragma unroll
        for (int kc = 0; kc < 4; kc++)
            hf[kc] = *(const short8*)(bufB + l15 * 136 + kc * 32 + kq * 8);
        acc[0] = (f32x4){0.f, 0.f, 0.f, 0.f};
        acc[1] = (f32x4){0.f, 0.f, 0.f, 0.f};
        bc[0] = bias2[nt0 * 16 + l15];
        bc[1] = bias2[(nt0 + 1) * 16 + l15];
#pragma unroll
        for (int kc = 0; kc < 4; kc++) {
#pragma unroll
            for (int u = 0; u < 2; u++) {
                const size_t woff = (size_t)((nt0 + u) * 16 + l15) * 128 + kc * 32 + kq * 8;
                acc[u] = __builtin_amdgcn_mfma_f32_16x16x32_bf16(
                    hf[kc], *(const short8*)(W2 + woff), acc[u], 0, 0, 0);
            }
        }
    }

    if (POOL) {
        bool same = (g[0] == g[1]) && (g[1] == g[2]) && (g[2] == g[3]) && (g[0] >= 0);
#pragma unroll
        for (int u = 0; u < 2; u++) {
            int c = (nt0 + u) * 16 + l15;
            float v0 = fmaxf(acc[u][0] + bc[u], 0.f);
            float v1 = fmaxf(acc[u][1] + bc[u], 0.f);
            float v2 = fmaxf(acc[u][2] + bc[u], 0.f);
            float v3 = fmaxf(acc[u][3] + bc[u], 0.f);
            if (same) {
                int si = g[0] - gmin;
                float s4 = (v0 + v1) + (v2 + v3);
                if (si < 4) atomicAdd(&pbuf[si * 128 + c], s4);
                else        atomicAdd(&pool[g[0] * 128 + c], s4);
            } else {
                float vr[4] = {v0, v1, v2, v3};
#pragma unroll
                for (int r = 0; r < 4; r++) {
                    if (g[r] >= 0) {
                        int si = g[r] - gmin;
                        if (si < 4) atomicAdd(&pbuf[si * 128 + c], vr[r]);
                        else        atomicAdd(&pool[g[r] * 128 + c], vr[r]);
                    }
                }
            }
        }
        __syncthreads();
        for (int i = t; i < 512; i += 256) {
            float v = pbuf[i];
            if (v != 0.f)
                atomicAdd(&pool[(gmin + (i >> 7)) * 128 + (i & 127)], v);
        }
        // ---- last-block fused fc
        __threadfence();
        __syncthreads();
        if (t == 0) ticket_s = atomicAdd(done, 1);
        __syncthreads();
        if (ticket_s == (int)gridDim.x - 1) {
            __threadfence();
            int isbf = flags0;
            if (t <= G) {
                int lo = 0, hi = N;
                while (lo < hi) {
                    int mid = (lo + hi) >> 1;
                    int bv = f64 ? batch[2 * mid] : batch[mid];
                    if (bv < t) lo = mid + 1; else hi = mid;
                }
                gst_s[t] = lo;
            }
            __syncthreads();
            if (t < G * 3) {
                int gg = t / 3, o = t % 3;
                int cc = gst_s[gg + 1] - gst_s[gg];
                float inv = 1.f / fmaxf((float)cc, 1.f);
                float a2 = 0.f;
                for (int k = 0; k < 128; k++) {
                    float pv = __hip_atomic_load(&pool[gg * 128 + k],
                                                 __ATOMIC_RELAXED,
                                                 __HIP_MEMORY_SCOPE_AGENT);
                    a2 += pv * fcW[o * 128 + k];
                }
                float r = a2 * inv + fcb[o];
                if (isbf) ((__hip_bfloat16*)out)[t] = __float2bfloat16(r);
                else      ((float*)out)[t] = r;
            }
        }
    } else {
#pragma unroll
        for (int u = 0; u < 2; u++) {
#pragma unroll
            for (int r = 0; r < 4; r++) {
                bufA[(kq * 4 + r) * 136 + (nt0 + u) * 16 + l15] =
                    f2bf(fmaxf(acc[u][r] + bc[u], 0.f));
            }
        }
        __syncthreads();
        int row = t >> 4, colsh = (t & 15) * 8;
        uint4 val = *(const uint4*)(bufA + row * 136 + colsh);
        if (m0 + row < N) {
            *(uint4*)(Hdst + (size_t)(m0 + row) * 128 + colsh) = val;
            // fp8 shadow write
            float h0 = bits2f(val.x << 16), h1 = bits2f(val.x & 0xffff0000u);
            float h2 = bits2f(val.y << 16), h3 = bits2f(val.y & 0xffff0000u);
            float h4 = bits2f(val.z << 16), h5 = bits2f(val.z & 0xffff0000u);
            float h6 = bits2f(val.w << 16), h7 = bits2f(val.w & 0xffff0000u);
            uint2 e8;
            e8.x = pk4fp8(h0, h1, h2, h3);
            e8.y = pk4fp8(h4, h5, h6, h7);
            Hdst8[(size_t)(m0 + row) * 16 + (colsh >> 3)] = e8;
        }
    }
}

// distinctly-named instantiations (rocprof visibility)
__global__ __launch_bounds__(256) void conv01_kernel(
    const void* xsel, const unsigned short* __restrict__ Hbuf,
    const uint2* __restrict__ G8,
    const int* __restrict__ cnt, const int* __restrict__ nbr,
    const unsigned short* __restrict__ Wl, const unsigned short* __restrict__ Wr,
    const float* __restrict__ bias,
    const unsigned short* __restrict__ W2, const float* __restrict__ bias2,
    unsigned short* __restrict__ Hdst, uint2* __restrict__ Hdst8,
    const int* __restrict__ flags, int N) {
    conv_core<true, false>(xsel, Hbuf, G8, cnt, nbr, Wl, Wr, bias, W2, bias2,
                           Hdst, Hdst8, nullptr, nullptr, flags, N,
                           nullptr, nullptr, nullptr, nullptr, 0);
}

__global__ __launch_bounds__(256) void conv1p_kernel(
    const unsigned short* __restrict__ Hbuf, const uint2* __restrict__ G8,
    const int* __restrict__ cnt, const int* __restrict__ nbr,
    const unsigned short* __restrict__ Wl, const unsigned short* __restrict__ Wr,
    const float* __restrict__ bias,
    float* __restrict__ pool, const int* __restrict__ batch,
    const int* __restrict__ flags, int N,
    int* __restrict__ done, const float* __restrict__ fcW,
    const float* __restrict__ fcb, void* __restrict__ out, int G) {
    conv_core<false, true>(Hbuf, Hbuf, G8, cnt, nbr, Wl, Wr, bias,
                           nullptr, nullptr, nullptr, nullptr, pool, batch,
                           flags, N, done, fcW, fcb, out, G);
}

extern "C" void kernel_launch(void* const* d_in, const int* in_sizes, int n_in,
                              void* d_out, int out_size, void* d_ws, size_t ws_size,
                              hipStream_t stream) {
    const void* x   = d_in[0];
    const void* W0l = d_in[1];
    const void* b0l = d_in[2];
    const void* W0r = d_in[3];
    const void* W1  = d_in[4];
    const void* b1  = d_in[5];
    const void* W1l = d_in[6];
    const void* b1l = d_in[7];
    const void* W1r = d_in[8];
    const void* fcW = d_in[9];
    const void* fcb = d_in[10];
    const int* edge_index = (const int*)d_in[11];
    const int* batch      = (const int*)d_in[12];

    const int N = in_sizes[12];        // 50000
    const int E = in_sizes[11] / 2;    // 600000
    const int G = out_size / 3;        // 32

    char* ws = (char*)d_ws;
    auto align64 = [](size_t v) { return (v + 63) & ~(size_t)63; };
    size_t off = 0;
    size_t OFF_CNT  = off; off = align64(off + (size_t)N * 4);
    size_t OFF_POOL = off; off = align64(off + (size_t)G * 128 * 4);
    size_t OFF_DONE = off; off = align64(off + 64);
    size_t MEMSET_BYTES = off;              // cnt + pool + done zeroed together
    size_t OFF_FLAGS = off; off = align64(off + 64);
    size_t OFF_NBR  = off; off = align64(off + (size_t)N * 64 * 4);
    size_t OFF_WB   = off; off = align64(off + (size_t)WB_TOTAL * 2);
    size_t OFF_CF   = off; off = align64(off + (size_t)CF_TOTAL * 4);
    size_t OFF_XF8  = off; off = align64(off + (size_t)N * 128);
    size_t OFF_H2F8 = off; off = align64(off + (size_t)N * 128);
    size_t OFF_HB   = off; off = align64(off + ((size_t)N + 64) * 128 * 2);
    size_t OFF_H2   = off; off = align64(off + ((size_t)N + 64) * 128 * 2);
    (void)ws_size;

    int*    cnt    = (int*)(ws + OFF_CNT);
    float*  pool   = (float*)(ws + OFF_POOL);
    int*    done   = (int*)(ws + OFF_DONE);
    int*    flags  = (int*)(ws + OFF_FLAGS);
    int*    nbr    = (int*)(ws + OFF_NBR);
    unsigned short* wb = (unsigned short*)(ws + OFF_WB);
    float*  cf     = (float*)(ws + OFF_CF);
    uint2*  Xf8    = (uint2*)(ws + OFF_XF8);
    uint2*  H2f8   = (uint2*)(ws + OFF_H2F8);
    unsigned short* Hb = (unsigned short*)(ws + OFF_HB);
    unsigned short* H2 = (unsigned short*)(ws + OFF_H2);

    hipMemsetAsync(ws, 0, MEMSET_BYTES, stream);

    int n8 = (N * 128) / 8;
    int EG  = (E + 255) / 256;
    int WC  = (WB_TOTAL + CF_TOTAL + 255) / 256;
    int CVT = (n8 + 255) / 256;
    prep_kernel<<<EG + WC + CVT, 256, 0, stream>>>(
        x, edge_index, W0l, W0r, W1, W1l, W1r, b0l, b1, b1l, fcW, fcb,
        Hb, Xf8, wb, cf, cnt, nbr, flags, n8, E, EG, WC);

    int cgrid = (N + 15) / 16;

    // conv0 + lin1 fused:  h2 = relu(relu(mean@W0l^T + x@W0r^T + b0l)@W1^T + b1)
    conv01_kernel<<<cgrid, 256, 0, stream>>>(
        x, Hb, Xf8, cnt, nbr, wb + WB_W0L, wb + WB_W0R, cf + CF_B0L,
        wb + WB_W1, cf + CF_B1, H2, H2f8, flags, N);

    // conv1 + pool + fc fused (last-block ticket)
    conv1p_kernel<<<cgrid, 256, 0, stream>>>(
        H2, H2f8, cnt, nbr, wb + WB_W1L, wb + WB_W1R, cf + CF_B1L,
        pool, batch, flags, N, done, cf + CF_FCW, cf + CF_FCB, d_out, G);

    (void)in_sizes; (void)n_in; (void)out_size;
}

// Round 9
// 240.887 us; speedup vs baseline: 1.9664x; 1.9664x over previous
//
#include <hip/hip_runtime.h>
#include <hip/hip_bf16.h>
#include <stdint.h>

// ---------------------------------------------------------------------------
// StaticGNN: SAGEConv(mean) -> ReLU -> Linear -> ReLU -> SAGEConv(mean) ->
//            ReLU -> global_mean_pool -> fc
// Round 9: round-8 fp8-shadow gather KEPT (FETCH 87->33MB, same absmax);
// fc-in-conv1p fusion REVERTED (its per-block __threadfence = agent-scope
// L2 writeback serialized ~230us across 3125 blocks). Standalone fc_kernel
// returns; launch boundary provides coherence. 5 dispatches.
// ---------------------------------------------------------------------------

typedef __attribute__((ext_vector_type(8))) short short8;
typedef __attribute__((ext_vector_type(4))) float f32x4;
typedef __attribute__((ext_vector_type(2))) float f32x2;

__device__ __forceinline__ float bits2f(uint32_t b) {
    union { uint32_t u; float f; } c; c.u = b; return c.f;
}
__device__ __forceinline__ unsigned short f2bf(float f) {
    __hip_bfloat16 h = __float2bfloat16(f);
    union { __hip_bfloat16 h; unsigned short u; } c; c.h = h; return c.u;
}
__device__ __forceinline__ uint32_t pack2bf(float a, float b) {
    return (uint32_t)f2bf(a) | ((uint32_t)f2bf(b) << 16);
}
// 4 floats -> 4 fp8 e4m3 packed in a uint (HW cvt, OCP on gfx950)
__device__ __forceinline__ uint32_t pk4fp8(float f0, float f1, float f2, float f3) {
    int o = 0;
    o = __builtin_amdgcn_cvt_pk_fp8_f32(f0, f1, o, false);
    o = __builtin_amdgcn_cvt_pk_fp8_f32(f2, f3, o, true);
    return (uint32_t)o;
}
// accumulate 8 fp8 values (uint2) into fp32 acc
__device__ __forceinline__ void acc8f8(float* a, uint2 v) {
    f32x2 p0 = __builtin_amdgcn_cvt_pk_f32_fp8((int)v.x, false);
    f32x2 p1 = __builtin_amdgcn_cvt_pk_f32_fp8((int)v.x, true);
    f32x2 p2 = __builtin_amdgcn_cvt_pk_f32_fp8((int)v.y, false);
    f32x2 p3 = __builtin_amdgcn_cvt_pk_f32_fp8((int)v.y, true);
    a[0] += p0.x; a[1] += p0.y; a[2] += p1.x; a[3] += p1.y;
    a[4] += p2.x; a[5] += p2.y; a[6] += p3.x; a[7] += p3.y;
}

// wave-local dtype detection
__device__ __forceinline__ void detect_flags(const unsigned short* x,
                                             const int* ei,
                                             int& isbf, int& is64) {
    int lane = threadIdx.x & 63;
    unsigned short h = x[lane];
    int e = (h >> 7) & 0xFF;
    unsigned long long mbf = __ballot(e >= 102 && e <= 137);
    unsigned long long m64 = __ballot(ei[2 * lane + 1] != 0);
    isbf = (__popcll(mbf) >= 52) ? 1 : 0;
    is64 = (m64 == 0ULL) ? 1 : 0;
}

// ----- fused prep: flags + bucket-adjacency + wcvt + x->fp8 (+bf16) ------
#define WB_W0L 0
#define WB_W0R 16384
#define WB_W1  32768
#define WB_W1L 49152
#define WB_W1R 65536
#define WB_TOTAL 81920
#define CF_B0L 0
#define CF_B1  128
#define CF_B1L 256
#define CF_FCW 384
#define CF_FCB 768
#define CF_TOTAL 771

__global__ __launch_bounds__(256) void prep_kernel(
    const void* x, const int* __restrict__ ei,
    const void* s0, const void* s1, const void* s2, const void* s3,
    const void* s4, const void* f0, const void* f1, const void* f2,
    const void* f3, const void* f4,
    unsigned short* __restrict__ Hb, uint2* __restrict__ Xf8,
    unsigned short* __restrict__ wb,
    float* __restrict__ cf, int* __restrict__ cnt, int* __restrict__ nbr,
    int* __restrict__ flags, int n8, int E, int EG, int WC) {
    int isbf, is64;
    detect_flags((const unsigned short*)x, ei, isbf, is64);
    int b = blockIdx.x;
    if (b == 0 && threadIdx.x == 0) { flags[0] = isbf; flags[1] = is64; }

    if (b < EG) {
        // bucket-adjacency build: one pass over edges
        int e = b * 256 + threadIdx.x;
        if (e >= E) return;
        int s, d;
        if (is64) { s = ei[2 * e]; d = ei[2 * (E + e)]; }
        else      { s = ei[e];     d = ei[E + e]; }
        int pos = atomicAdd(&cnt[d], 1);
        if (pos < 64) nbr[((size_t)d << 6) + pos] = s;
    } else if (b < EG + WC) {
        int i = (b - EG) * 256 + threadIdx.x;
        if (i < WB_TOTAL) {
            const void* p; int k = i & 16383;
            switch (i >> 14) {
                case 0: p = s0; break;
                case 1: p = s1; break;
                case 2: p = s2; break;
                case 3: p = s3; break;
                default: p = s4; break;
            }
            wb[i] = isbf ? ((const unsigned short*)p)[k]
                         : f2bf(((const float*)p)[k]);
        } else {
            int j = i - WB_TOTAL;
            if (j >= CF_TOTAL) return;
            const void* p; int k;
            if      (j < CF_B1)  { p = f0; k = j; }
            else if (j < CF_B1L) { p = f1; k = j - CF_B1; }
            else if (j < CF_FCW) { p = f2; k = j - CF_B1L; }
            else if (j < CF_FCB) { p = f3; k = j - CF_FCW; }
            else                 { p = f4; k = j - CF_FCB; }
            cf[j] = isbf ? bits2f((uint32_t)((const unsigned short*)p)[k] << 16)
                         : ((const float*)p)[k];
        }
    } else {
        // x -> fp8 shadow (always); fp32 input additionally -> bf16 Hb
        int i = (b - EG - WC) * 256 + threadIdx.x;
        if (i >= n8) return;
        float f[8];
        if (isbf) {
            uint4 d = ((const uint4*)x)[i];
            f[0] = bits2f(d.x << 16); f[1] = bits2f(d.x & 0xffff0000u);
            f[2] = bits2f(d.y << 16); f[3] = bits2f(d.y & 0xffff0000u);
            f[4] = bits2f(d.z << 16); f[5] = bits2f(d.z & 0xffff0000u);
            f[6] = bits2f(d.w << 16); f[7] = bits2f(d.w & 0xffff0000u);
        } else {
            float4 a = ((const float4*)x)[2 * i];
            float4 c = ((const float4*)x)[2 * i + 1];
            f[0] = a.x; f[1] = a.y; f[2] = a.z; f[3] = a.w;
            f[4] = c.x; f[5] = c.y; f[6] = c.z; f[7] = c.w;
            uint4 d;
            d.x = pack2bf(f[0], f[1]); d.y = pack2bf(f[2], f[3]);
            d.z = pack2bf(f[4], f[5]); d.w = pack2bf(f[6], f[7]);
            ((uint4*)Hb)[i] = d;
        }
        uint2 o8;
        o8.x = pk4fp8(f[0], f[1], f[2], f[3]);
        o8.y = pk4fp8(f[4], f[5], f[6], f[7]);
        Xf8[i] = o8;
    }
}

// ----- fused conv core: 16 rows/block, 4 waves ---------------------------
// gather reads the fp8 shadow (128 B/row); self-term reads bf16.
template <bool LIN1, bool POOL>
__device__ __forceinline__ void conv_core(
    const void* xsel, const unsigned short* __restrict__ Hbuf,
    const uint2* __restrict__ G8,
    const int* __restrict__ cnt, const int* __restrict__ nbr,
    const unsigned short* __restrict__ Wl, const unsigned short* __restrict__ Wr,
    const float* __restrict__ bias,
    const unsigned short* __restrict__ W2, const float* __restrict__ bias2,
    unsigned short* __restrict__ Hdst, uint2* __restrict__ Hdst8,
    float* __restrict__ pool, const int* __restrict__ batch,
    const int* __restrict__ flags, int N) {
    __shared__ unsigned short bufA[16 * 136];
    __shared__ unsigned short bufB[LIN1 ? 16 * 136 : 1];
    __shared__ float pbuf[POOL ? 512 : 1];
    const int t = threadIdx.x;
    const int lane = t & 63;
    const int w = t >> 6;
    const int l15 = lane & 15;
    const int kq = lane >> 4;
    const int m0 = blockIdx.x * 16;

    const int flags0 = flags[0];
    const unsigned short* Hs = flags0 ? (const unsigned short*)xsel : Hbuf;

    int f64 = 0, gmin = 0, g[4];
    if (POOL) {
        f64 = flags[1];
        gmin = f64 ? batch[2 * m0] : batch[m0];
#pragma unroll
        for (int r = 0; r < 4; r++) {
            int gr = m0 + kq * 4 + r;
            g[r] = (gr < N) ? (f64 ? batch[2 * gr] : batch[gr]) : -1;
        }
        for (int i = t; i < 512; i += 256) pbuf[i] = 0.f;
    }

    // prefetch x-frag (overlaps gather latency); clamp tail rows
    short8 xf[4];
    {
        int xr = m0 + l15; if (xr >= N) xr = N - 1;
        const unsigned short* xrow = Hs + (size_t)xr * 128 + kq * 8;
#pragma unroll
        for (int kc = 0; kc < 4; kc++) xf[kc] = *(const short8*)(xrow + kc * 32);
    }
    float bc[2];
    const int nt0 = w * 2;
    bc[0] = bias[nt0 * 16 + l15];
    bc[1] = bias[(nt0 + 1) * 16 + l15];

    // ---- phase 1: fp8 gather-mean; quarter kq of wave w handles row w*4+kq
    {
        const int row = w * 4 + kq;
        const int node = m0 + row;
        float a[8] = {0.f, 0.f, 0.f, 0.f, 0.f, 0.f, 0.f, 0.f};
        float invd = 0.f;
        if (node < N) {
            int dcnt = cnt[node];
            invd = 1.f / fmaxf((float)dcnt, 1.f);
            if (dcnt > 64) dcnt = 64;
            const int* nrow = nbr + ((size_t)node << 6);
            for (int base = 0; base < dcnt; base += 16) {
                int c = dcnt - base; if (c > 16) c = 16;
                int idx = (l15 < c) ? nrow[base + l15] : 0;
                int it = 0;
                for (; it + 4 <= c; it += 4) {
                    int j0 = __shfl(idx, kq * 16 + it, 64);
                    int j1 = __shfl(idx, kq * 16 + it + 1, 64);
                    int j2 = __shfl(idx, kq * 16 + it + 2, 64);
                    int j3 = __shfl(idx, kq * 16 + it + 3, 64);
                    uint2 v0 = G8[(size_t)j0 * 16 + l15];
                    uint2 v1 = G8[(size_t)j1 * 16 + l15];
                    uint2 v2 = G8[(size_t)j2 * 16 + l15];
                    uint2 v3 = G8[(size_t)j3 * 16 + l15];
                    acc8f8(a, v0); acc8f8(a, v1); acc8f8(a, v2); acc8f8(a, v3);
                }
                for (; it < c; ++it) {
                    int j = __shfl(idx, kq * 16 + it, 64);
                    acc8f8(a, G8[(size_t)j * 16 + l15]);
                }
            }
        }
        uint4 o;
        o.x = pack2bf(a[0] * invd, a[1] * invd);
        o.y = pack2bf(a[2] * invd, a[3] * invd);
        o.z = pack2bf(a[4] * invd, a[5] * invd);
        o.w = pack2bf(a[6] * invd, a[7] * invd);
        *(uint4*)(bufA + row * 136 + l15 * 8) = o;
    }
    __syncthreads();

    // ---- phase 2: MFMA; wave w owns col tiles nt0, nt0+1
    short8 af[4];
#pragma unroll
    for (int kc = 0; kc < 4; kc++)
        af[kc] = *(const short8*)(bufA + l15 * 136 + kc * 32 + kq * 8);

    f32x4 acc[2];
    acc[0] = (f32x4){0.f, 0.f, 0.f, 0.f};
    acc[1] = (f32x4){0.f, 0.f, 0.f, 0.f};
#pragma unroll
    for (int kc = 0; kc < 4; kc++) {
#pragma unroll
        for (int u = 0; u < 2; u++) {
            const size_t woff = (size_t)((nt0 + u) * 16 + l15) * 128 + kc * 32 + kq * 8;
            acc[u] = __builtin_amdgcn_mfma_f32_16x16x32_bf16(
                xf[kc], *(const short8*)(Wr + woff), acc[u], 0, 0, 0);
            acc[u] = __builtin_amdgcn_mfma_f32_16x16x32_bf16(
                af[kc], *(const short8*)(Wl + woff), acc[u], 0, 0, 0);
        }
    }

    if (LIN1) {
#pragma unroll
        for (int u = 0; u < 2; u++) {
#pragma unroll
            for (int r = 0; r < 4; r++) {
                bufB[(kq * 4 + r) * 136 + (nt0 + u) * 16 + l15] =
                    f2bf(fmaxf(acc[u][r] + bc[u], 0.f));
            }
        }
        __syncthreads();
        short8 hf[4];
#pragma unroll
        for (int kc = 0; kc < 4; kc++)
            hf[kc] = *(const short8*)(bufB + l15 * 136 + kc * 32 + kq * 8);
        acc[0] = (f32x4){0.f, 0.f, 0.f, 0.f};
        acc[1] = (f32x4){0.f, 0.f, 0.f, 0.f};
        bc[0] = bias2[nt0 * 16 + l15];
        bc[1] = bias2[(nt0 + 1) * 16 + l15];
#pragma unroll
        for (int kc = 0; kc < 4; kc++) {
#pragma unroll
            for (int u = 0; u < 2; u++) {
                const size_t woff = (size_t)((nt0 + u) * 16 + l15) * 128 + kc * 32 + kq * 8;
                acc[u] = __builtin_amdgcn_mfma_f32_16x16x32_bf16(
                    hf[kc], *(const short8*)(W2 + woff), acc[u], 0, 0, 0);
            }
        }
    }

    if (POOL) {
        bool same = (g[0] == g[1]) && (g[1] == g[2]) && (g[2] == g[3]) && (g[0] >= 0);
#pragma unroll
        for (int u = 0; u < 2; u++) {
            int c = (nt0 + u) * 16 + l15;
            float v0 = fmaxf(acc[u][0] + bc[u], 0.f);
            float v1 = fmaxf(acc[u][1] + bc[u], 0.f);
            float v2 = fmaxf(acc[u][2] + bc[u], 0.f);
            float v3 = fmaxf(acc[u][3] + bc[u], 0.f);
            if (same) {
                int si = g[0] - gmin;
                float s4 = (v0 + v1) + (v2 + v3);
                if (si < 4) atomicAdd(&pbuf[si * 128 + c], s4);
                else        atomicAdd(&pool[g[0] * 128 + c], s4);
            } else {
                float vr[4] = {v0, v1, v2, v3};
#pragma unroll
                for (int r = 0; r < 4; r++) {
                    if (g[r] >= 0) {
                        int si = g[r] - gmin;
                        if (si < 4) atomicAdd(&pbuf[si * 128 + c], vr[r]);
                        else        atomicAdd(&pool[g[r] * 128 + c], vr[r]);
                    }
                }
            }
        }
        __syncthreads();
        for (int i = t; i < 512; i += 256) {
            float v = pbuf[i];
            if (v != 0.f)
                atomicAdd(&pool[(gmin + (i >> 7)) * 128 + (i & 127)], v);
        }
    } else {
#pragma unroll
        for (int u = 0; u < 2; u++) {
#pragma unroll
            for (int r = 0; r < 4; r++) {
                bufA[(kq * 4 + r) * 136 + (nt0 + u) * 16 + l15] =
                    f2bf(fmaxf(acc[u][r] + bc[u], 0.f));
            }
        }
        __syncthreads();
        int row = t >> 4, colsh = (t & 15) * 8;
        uint4 val = *(const uint4*)(bufA + row * 136 + colsh);
        if (m0 + row < N) {
            *(uint4*)(Hdst + (size_t)(m0 + row) * 128 + colsh) = val;
            // fp8 shadow write
            float h0 = bits2f(val.x << 16), h1 = bits2f(val.x & 0xffff0000u);
            float h2 = bits2f(val.y << 16), h3 = bits2f(val.y & 0xffff0000u);
            float h4 = bits2f(val.z << 16), h5 = bits2f(val.z & 0xffff0000u);
            float h6 = bits2f(val.w << 16), h7 = bits2f(val.w & 0xffff0000u);
            uint2 e8;
            e8.x = pk4fp8(h0, h1, h2, h3);
            e8.y = pk4fp8(h4, h5, h6, h7);
            Hdst8[(size_t)(m0 + row) * 16 + (colsh >> 3)] = e8;
        }
    }
}

// distinctly-named instantiations (rocprof visibility)
__global__ __launch_bounds__(256) void conv01_kernel(
    const void* xsel, const unsigned short* __restrict__ Hbuf,
    const uint2* __restrict__ G8,
    const int* __restrict__ cnt, const int* __restrict__ nbr,
    const unsigned short* __restrict__ Wl, const unsigned short* __restrict__ Wr,
    const float* __restrict__ bias,
    const unsigned short* __restrict__ W2, const float* __restrict__ bias2,
    unsigned short* __restrict__ Hdst, uint2* __restrict__ Hdst8,
    const int* __restrict__ flags, int N) {
    conv_core<true, false>(xsel, Hbuf, G8, cnt, nbr, Wl, Wr, bias, W2, bias2,
                           Hdst, Hdst8, nullptr, nullptr, flags, N);
}

__global__ __launch_bounds__(256) void conv1p_kernel(
    const unsigned short* __restrict__ Hbuf, const uint2* __restrict__ G8,
    const int* __restrict__ cnt, const int* __restrict__ nbr,
    const unsigned short* __restrict__ Wl, const unsigned short* __restrict__ Wr,
    const float* __restrict__ bias,
    float* __restrict__ pool, const int* __restrict__ batch,
    const int* __restrict__ flags, int N) {
    conv_core<false, true>(Hbuf, Hbuf, G8, cnt, nbr, Wl, Wr, bias,
                           nullptr, nullptr, nullptr, nullptr, pool, batch,
                           flags, N);
}

// ----- final fc (gstart inlined) -----------------------------------------
__global__ void fc_kernel(const float* __restrict__ pool,
                          const int* __restrict__ batch,
                          const float* __restrict__ W,
                          const float* __restrict__ b,
                          void* __restrict__ out,
                          const int* __restrict__ flags, int N, int G) {
    __shared__ int gst[64];
    int t = threadIdx.x;
    int f64 = flags[1];
    int isbf = flags[0];
    if (t <= G) {
        int lo = 0, hi = N;
        while (lo < hi) {
            int mid = (lo + hi) >> 1;
            int bv = f64 ? batch[2 * mid] : batch[mid];
            if (bv < t) lo = mid + 1; else hi = mid;
        }
        gst[t] = lo;
    }
    __syncthreads();
    if (t >= G * 3) return;
    int g = t / 3, o = t % 3;
    int cnt = gst[g + 1] - gst[g];
    float inv = 1.f / fmaxf((float)cnt, 1.f);
    float acc = 0.f;
    for (int k = 0; k < 128; k++)
        acc += pool[g * 128 + k] * W[o * 128 + k];
    float r = acc * inv + b[o];
    if (isbf) ((__hip_bfloat16*)out)[t] = __float2bfloat16(r);
    else      ((float*)out)[t] = r;
}

extern "C" void kernel_launch(void* const* d_in, const int* in_sizes, int n_in,
                              void* d_out, int out_size, void* d_ws, size_t ws_size,
                              hipStream_t stream) {
    const void* x   = d_in[0];
    const void* W0l = d_in[1];
    const void* b0l = d_in[2];
    const void* W0r = d_in[3];
    const void* W1  = d_in[4];
    const void* b1  = d_in[5];
    const void* W1l = d_in[6];
    const void* b1l = d_in[7];
    const void* W1r = d_in[8];
    const void* fcW = d_in[9];
    const void* fcb = d_in[10];
    const int* edge_index = (const int*)d_in[11];
    const int* batch      = (const int*)d_in[12];

    const int N = in_sizes[12];        // 50000
    const int E = in_sizes[11] / 2;    // 600000
    const int G = out_size / 3;        // 32

    char* ws = (char*)d_ws;
    auto align64 = [](size_t v) { return (v + 63) & ~(size_t)63; };
    size_t off = 0;
    size_t OFF_CNT  = off; off = align64(off + (size_t)N * 4);
    size_t OFF_POOL = off; off = align64(off + (size_t)G * 128 * 4);
    size_t MEMSET_BYTES = off;              // cnt + pool zeroed together
    size_t OFF_FLAGS = off; off = align64(off + 64);
    size_t OFF_NBR  = off; off = align64(off + (size_t)N * 64 * 4);
    size_t OFF_WB   = off; off = align64(off + (size_t)WB_TOTAL * 2);
    size_t OFF_CF   = off; off = align64(off + (size_t)CF_TOTAL * 4);
    size_t OFF_XF8  = off; off = align64(off + (size_t)N * 128);
    size_t OFF_H2F8 = off; off = align64(off + (size_t)N * 128);
    size_t OFF_HB   = off; off = align64(off + ((size_t)N + 64) * 128 * 2);
    size_t OFF_H2   = off; off = align64(off + ((size_t)N + 64) * 128 * 2);
    (void)ws_size;

    int*    cnt    = (int*)(ws + OFF_CNT);
    float*  pool   = (float*)(ws + OFF_POOL);
    int*    flags  = (int*)(ws + OFF_FLAGS);
    int*    nbr    = (int*)(ws + OFF_NBR);
    unsigned short* wb = (unsigned short*)(ws + OFF_WB);
    float*  cf     = (float*)(ws + OFF_CF);
    uint2*  Xf8    = (uint2*)(ws + OFF_XF8);
    uint2*  H2f8   = (uint2*)(ws + OFF_H2F8);
    unsigned short* Hb = (unsigned short*)(ws + OFF_HB);
    unsigned short* H2 = (unsigned short*)(ws + OFF_H2);

    hipMemsetAsync(ws, 0, MEMSET_BYTES, stream);

    int n8 = (N * 128) / 8;
    int EG  = (E + 255) / 256;
    int WC  = (WB_TOTAL + CF_TOTAL + 255) / 256;
    int CVT = (n8 + 255) / 256;
    prep_kernel<<<EG + WC + CVT, 256, 0, stream>>>(
        x, edge_index, W0l, W0r, W1, W1l, W1r, b0l, b1, b1l, fcW, fcb,
        Hb, Xf8, wb, cf, cnt, nbr, flags, n8, E, EG, WC);

    int cgrid = (N + 15) / 16;

    // conv0 + lin1 fused:  h2 = relu(relu(mean@W0l^T + x@W0r^T + b0l)@W1^T + b1)
    conv01_kernel<<<cgrid, 256, 0, stream>>>(
        x, Hb, Xf8, cnt, nbr, wb + WB_W0L, wb + WB_W0R, cf + CF_B0L,
        wb + WB_W1, cf + CF_B1, H2, H2f8, flags, N);

    // conv1 + pool fused:  pool += relu(mean(h2)@W1l^T + h2@W1r^T + b1l)
    conv1p_kernel<<<cgrid, 256, 0, stream>>>(
        H2, H2f8, cnt, nbr, wb + WB_W1L, wb + WB_W1R, cf + CF_B1L,
        pool, batch, flags, N);

    fc_kernel<<<1, 128, 0, stream>>>(pool, batch, cf + CF_FCW, cf + CF_FCB,
                                     d_out, flags, N, G);

    (void)in_sizes; (void)n_in; (void)out_size;
}